// Round 3
// baseline (104.231 us; speedup 1.0000x reference)
//
#include <hip/hip_runtime.h>
#include <math.h>

#define J   29
#define CH  3
#define JC  87            // J*CH
#define E0  56
#define B   256
#define T   1024
#define FRAMES (B*T)      // 262144
#define FPC 64            // frames per chunk (= wave size)
#define CPB 4             // chunks per block (contiguous, same batch)
#define NBLK (FRAMES/(FPC*CPB)) // 1024
#define CHUNK_FLOATS (FPC*JC)   // 5568 floats = 22272 B
#define BPB 4             // partials per batch in finalize

typedef const __attribute__((address_space(1))) void* gas_p;
typedef __attribute__((address_space(3))) void* las_p;

// ---------------- prep: build CSR of M = D^-1/2 (A+I) D^-1/2 ----------------
__global__ void prep_kernel(const int* __restrict__ ei,
                            int* __restrict__ rowptr,
                            int* __restrict__ cols,
                            float* __restrict__ vals) {
    __shared__ float M[J * J];
    __shared__ float dinv[J];
    __shared__ int   cnt[J];
    int tid = threadIdx.x;

    for (int i = tid; i < J * J; i += 64) M[i] = 0.f;
    if (tid < J) {
        int d = 1;  // self loop
        for (int e = 0; e < E0; ++e) d += (ei[E0 + e] == tid) ? 1 : 0;
        dinv[tid] = rsqrtf((float)d);
    }
    __syncthreads();

    if (tid < J) {
        for (int e = 0; e < E0; ++e) {
            if (ei[E0 + e] == tid) {
                int s = ei[e];
                M[tid * J + s] += dinv[s] * dinv[tid];
            }
        }
        M[tid * J + tid] += dinv[tid] * dinv[tid];
        int c = 0;
        for (int i = 0; i < J; ++i) c += (M[tid * J + i] != 0.f) ? 1 : 0;
        cnt[tid] = c;
    }
    __syncthreads();

    if (tid == 0) {
        int acc = 0;
        for (int j = 0; j < J; ++j) { rowptr[j] = acc; acc += cnt[j]; }
        rowptr[J] = acc;
    }
    __syncthreads();

    if (tid < J) {
        int p = rowptr[tid];
        for (int i = 0; i < J; ++i) {
            float v = M[tid * J + i];
            if (v != 0.f) { cols[p] = i; vals[p] = v; ++p; }
        }
    }
}

// stage one 64-frame chunk (22272 B) into LDS: 21 x 1024B rounds of 16B/lane
// plus one tail round at byte 21248 (re-writes 256B with identical data — benign).
// All ops are the HW-proven 16B width; 22 vmem ops total.
__device__ __forceinline__ void stage_chunk(const float* __restrict__ src,
                                            float* dst_lds, int lane) {
    const char* s = (const char*)src;
    char* d = (char*)dst_lds;
#pragma unroll
    for (int i = 0; i < 21; ++i) {
        __builtin_amdgcn_global_load_lds((gas_p)(s + i * 1024 + lane * 16),
                                         (las_p)(d + i * 1024), 16, 0, 0);
    }
    __builtin_amdgcn_global_load_lds((gas_p)(s + 21248 + lane * 16),
                                     (las_p)(d + 21248), 16, 0, 0);
}

// ---------------- main: 1 wave/block, 4 chunks, double-buffered staging -----
// Overlap structure needs only vmcnt(0): at each wait point the only
// outstanding vmem ops are the chunk we're about to read; the NEXT chunk is
// issued after the wait so it stays in flight across the compute.
__launch_bounds__(64)
__global__ void gcn_main(const float* __restrict__ x,
                         const float* __restrict__ Wp,
                         const float* __restrict__ bp,
                         const int* __restrict__ rowptr,
                         const int* __restrict__ cols,
                         const float* __restrict__ vals,
                         float* __restrict__ partials) {
    __shared__ float xs[2][CHUNK_FLOATS];   // 2 x 22272 B
    __shared__ int   s_rp[J + 1];
    __shared__ int   s_cols[85];
    __shared__ float s_vals[85];
    __shared__ float s_W[9];
    __shared__ float s_b[3];

    int lane = threadIdx.x;

    if (lane < 9)  s_W[lane] = Wp[lane];
    if (lane < 3)  s_b[lane] = bp[lane];
    if (lane <= J) s_rp[lane] = rowptr[lane];
    for (int i = lane; i < 85; i += 64) { s_cols[i] = cols[i]; s_vals[i] = vals[i]; }
    __syncthreads();   // drain small loads; no chunk staging in flight yet

    const float* src = x + (size_t)blockIdx.x * (CPB * CHUNK_FLOATS);
    stage_chunk(src, xs[0], lane);

    float acc[J][CH];
#pragma unroll
    for (int j = 0; j < J; ++j)
#pragma unroll
        for (int c = 0; c < CH; ++c) acc[j][c] = 0.f;

#pragma unroll
    for (int c = 0; c < CPB; ++c) {
        // wait for chunk c (the only outstanding vmem ops), then immediately
        // issue chunk c+1 so it flies during the compute below
        asm volatile("s_waitcnt vmcnt(0)" ::: "memory");
        __builtin_amdgcn_sched_barrier(0);
        if (c + 1 < CPB)
            stage_chunk(src + (size_t)(c + 1) * CHUNK_FLOATS, xs[(c + 1) & 1], lane);

        const float* xf = xs[c & 1] + lane * JC;
#pragma unroll
        for (int j = 0; j < J; ++j) {
            float a0 = 0.f, a1 = 0.f, a2 = 0.f;
            int e0 = s_rp[j], e1 = s_rp[j + 1];
            for (int e = e0; e < e1; ++e) {
                int   sc = s_cols[e] * CH;
                float nv = s_vals[e];
                a0 += nv * xf[sc + 0];
                a1 += nv * xf[sc + 1];
                a2 += nv * xf[sc + 2];
            }
#pragma unroll
            for (int ch = 0; ch < CH; ++ch) {
                float v = a0 * s_W[0 * CH + ch]
                        + a1 * s_W[1 * CH + ch]
                        + a2 * s_W[2 * CH + ch]
                        + s_b[ch];
                acc[j][ch] += fmaxf(v, 0.f);
            }
        }
    }

    // block-level reduce of 64 per-thread 87-vectors (reuse xs[0])
    float* red = xs[0];
#pragma unroll
    for (int j = 0; j < J; ++j)
#pragma unroll
        for (int ch = 0; ch < CH; ++ch)
            red[lane * JC + j * CH + ch] = acc[j][ch];
    __syncthreads();

#pragma unroll
    for (int s = 32; s >= 1; s >>= 1) {
        for (int w = lane; w < s * JC; w += 64) {
            int t = w % s, r = w / s;
            red[t * JC + r] += red[(t + s) * JC + r];
        }
        __syncthreads();
    }

    for (int w = lane; w < JC; w += 64)
        partials[(size_t)blockIdx.x * JC + w] = red[w];
}

// ---------------- finalize: mean over frames + fc + sigmoid ------------------
__global__ void finalize_kernel(const float* __restrict__ partials,
                                const float* __restrict__ fcW,
                                const float* __restrict__ fcb,
                                float* __restrict__ out) {
    __shared__ float h[JC];
    int b = blockIdx.x, tid = threadIdx.x;
    if (tid < JC) {
        float a = 0.f;
#pragma unroll
        for (int p = 0; p < BPB; ++p)
            a += partials[(size_t)(b * BPB + p) * JC + tid];
        a *= (1.0f / (float)T);
        h[tid] = a;
        out[(size_t)b * JC + tid] = a;
    }
    __syncthreads();
    if (tid < 2) {
        float a = fcb[tid];
        for (int r = 0; r < JC; ++r) a += h[r] * fcW[r * 2 + tid];
        out[(size_t)B * JC + b * 2 + tid] = 1.0f / (1.0f + expf(-a));
    }
}

extern "C" void kernel_launch(void* const* d_in, const int* in_sizes, int n_in,
                              void* d_out, int out_size, void* d_ws, size_t ws_size,
                              hipStream_t stream) {
    const float* x   = (const float*)d_in[0];
    const int*   ei  = (const int*)d_in[1];
    const float* W   = (const float*)d_in[4];
    const float* bb  = (const float*)d_in[5];
    const float* fcW = (const float*)d_in[6];
    const float* fcb = (const float*)d_in[7];

    int*   wsI      = (int*)d_ws;
    int*   rowptr   = wsI;                 // [30]
    int*   cols     = wsI + 32;            // [85]
    float* vals     = (float*)(wsI + 128); // [85]
    float* partials = (float*)(wsI + 256); // [1024*87]

    prep_kernel<<<1, 64, 0, stream>>>(ei, rowptr, cols, vals);
    gcn_main<<<NBLK, 64, 0, stream>>>(x, W, bb, rowptr, cols, vals, partials);
    finalize_kernel<<<B, 128, 0, stream>>>(partials, fcW, fcb, (float*)d_out);
}